// Round 15
// baseline (300.630 us; speedup 1.0000x reference)
//
#include <hip/hip_runtime.h>
#include <hip/hip_bf16.h>

// TransformerLayer: B=2, T=2048, C=768, H=12, D=64, FF=3072. fp32 I/O.
// Round 26: attn bias-preload hoist. The per-tile softmax C-init reads 16
// bias floats from LDS; the WAITVM "memory" clobber pinned those ds_reads
// AFTER the vmcnt wait -> serial LDS latency before the first QK MFMA.
// Now loaded into registers BEFORE the wait (bias_blk is read-only after
// the prologue barrier; reads depend only on bofs) so they drain under the
// K-load wait. Everything else = r25 best.
//
// Workspace layout (bytes):
//   0         QKVqk bf16 4096x1536 (q|k)      }
//   12582912  VT    bf16 768x4096 (V^T)       } Fb (bf16 4096x3072) aliases
//   18874368  Ob    bf16 4096x768             } [0, 25165824)
//   25165824  X2   fp32 4096x768
//   37748736  Hb   bf16 4096x768 (LN1/LN2 out)
//   44040192  Wqkv bf16 2304x768
//   47579136  Wob  bf16 768x768
//   48758784  W1b  bf16 3072x768
//   53477376  W2b  bf16 768x3072
//   58195968  bqkv fp32 2304
//   58205184  bias_rel fp32 12x4095 (pre-scaled by 1/ln2)
//   58401744  qpart fp32 2x64x64 (32 KB)
//   58434560  gate fp32 24

#define Tn 2048
#define Cn 768
#define Hn 12
#define Dn 64
#define FFn 3072
#define Mn 4096
#define QKVS 2304
#define LQK 1536

typedef __attribute__((ext_vector_type(8))) short bfrag;       // 8 bf16 (4 VGPR)
typedef __attribute__((ext_vector_type(8))) unsigned short us8;
typedef __attribute__((ext_vector_type(4))) float f32x4;

#define GLDS(gptr, lptr) __builtin_amdgcn_global_load_lds( \
    (const __attribute__((address_space(1))) void*)(gptr), \
    (__attribute__((address_space(3))) void*)(lptr), 16, 0, 0)

#define SBAR()   __builtin_amdgcn_s_barrier()
#define WAITVM(N) asm volatile("s_waitcnt vmcnt(" #N ")" ::: "memory")
#define WAITLG0() asm volatile("s_waitcnt lgkmcnt(0)" ::: "memory")

#define QSCALE 0.18033688f        // D^-0.5 / ln2, folded into Q at projection
#define INVQS  5.5451774445f      // 8 * ln2, gate compensation

__device__ __forceinline__ unsigned short f2bu(float f){
  __hip_bfloat16 h = __float2bfloat16(f);
  return *(unsigned short*)&h;
}
__device__ __forceinline__ float bu2f(unsigned short u){
  union { unsigned int i; float f; } v; v.i = ((unsigned int)u) << 16; return v.f;
}
__device__ __forceinline__ us8 pack8(float4 a, float4 b){
  us8 c;
  c[0]=f2bu(a.x); c[1]=f2bu(a.y); c[2]=f2bu(a.z); c[3]=f2bu(a.w);
  c[4]=f2bu(b.x); c[5]=f2bu(b.y); c[6]=f2bu(b.z); c[7]=f2bu(b.w);
  return c;
}
__device__ __forceinline__ float fexp2(float x){ return __builtin_amdgcn_exp2f(x); }

// ---- shared LN row body (fp32 in -> bf16 out; float4 loads, 1-pass) ----
__device__ __forceinline__ void ln_row_body(const float* __restrict__ xin,
    const float* __restrict__ w, const float* __restrict__ bsh,
    unsigned short* __restrict__ out, int row, float* sred /*[2][4]*/)
{
  const size_t base = (size_t)row * Cn;
  const int tid = threadIdx.x;
  float4 v = {0.f, 0.f, 0.f, 0.f};
  float s = 0.f, s2 = 0.f;
  if (tid < 192){
    v = *(const float4*)&xin[base + tid * 4];
    s  = (v.x + v.y) + (v.z + v.w);
    s2 = (v.x * v.x + v.y * v.y) + (v.z * v.z + v.w * v.w);
  }
  #pragma unroll
  for (int off = 32; off > 0; off >>= 1){
    s  += __shfl_down(s,  off, 64);
    s2 += __shfl_down(s2, off, 64);
  }
  if ((tid & 63) == 0){ sred[tid >> 6] = s; sred[4 + (tid >> 6)] = s2; }
  __syncthreads();
  const float ts  = (sred[0] + sred[1]) + (sred[2] + sred[3]);
  const float ts2 = (sred[4] + sred[5]) + (sred[6] + sred[7]);
  const float mean = ts * (1.f / Cn);
  const float var  = ts2 * (1.f / Cn) - mean * mean;
  const float rstd = rsqrtf(var + 1e-5f);
  if (tid < 192){
    const float4 wv = *(const float4*)&w[tid * 4];
    const float4 bv = *(const float4*)&bsh[tid * 4];
    const float o0 = (v.x - mean) * rstd * wv.x + bv.x;
    const float o1 = (v.y - mean) * rstd * wv.y + bv.y;
    const float o2 = (v.z - mean) * rstd * wv.z + bv.z;
    const float o3 = (v.w - mean) * rstd * wv.w + bv.w;
    uint2 pk;
    asm("v_cvt_pk_bf16_f32 %0, %1, %2" : "=v"(pk.x) : "v"(o0), "v"(o1));
    asm("v_cvt_pk_bf16_f32 %0, %1, %2" : "=v"(pk.y) : "v"(o2), "v"(o3));
    *(uint2*)&out[base + tid * 4] = pk;
  }
}

// ---- fused weight casts + bias_rel + bqkv + LN1 ----
// blocks: weights [0,3456); bias_rel [3456,3472); bqkv [3472,3481);
//         LN1 rows [3481, 3481+4096).
__global__ __launch_bounds__(256) void cast_ln_kernel(
    const float* __restrict__ wq, const float* __restrict__ wk,
    const float* __restrict__ wv, const float* __restrict__ wo,
    const float* __restrict__ w1, const float* __restrict__ w2,
    const float* __restrict__ bq, const float* __restrict__ bk,
    const float* __restrict__ bv, const float* __restrict__ rel_embed,
    unsigned short* __restrict__ Wqkv, unsigned short* __restrict__ Wob,
    unsigned short* __restrict__ W1b, unsigned short* __restrict__ W2b,
    float* __restrict__ bias_rel, float* __restrict__ bqkv,
    const float* __restrict__ x, const float* __restrict__ ln1_w,
    const float* __restrict__ ln1_b, unsigned short* __restrict__ Hb)
{
  __shared__ float sred[8];
  const int blk = blockIdx.x;
  if (blk >= 3481){
    ln_row_body(x, ln1_w, ln1_b, Hb, blk - 3481, sred);
    return;
  }
  if (blk >= 3472){
    const int i = (blk - 3472) * 256 + threadIdx.x;   // 0..2303 exactly
    bqkv[i] = (i < Cn) ? bq[i] : (i < 2 * Cn) ? bk[i - Cn] : bv[i - 2 * Cn];
    return;
  }
  if (blk >= 3456){
    const int idx = (blk - 3456) * 256 + threadIdx.x;
    if (idx >= 4095) return;
    const int rel = idx - 2047;
    const int ab = rel < 0 ? -rel : rel;
    int bucket;
    if (ab < 80){
      bucket = ab;
    } else {
      const float lr = logf((float)ab * (1.0f / 80.0f)) * (1.0f / 2.3025851f);
      int lp = 80 + (int)(lr * 80.0f);
      bucket = lp < 159 ? lp : 159;
    }
    if (rel >= 0) bucket += 160;
    #pragma unroll
    for (int h = 0; h < Hn; h++)
      bias_rel[h * 4095 + idx] = rel_embed[bucket * Hn + h] * 1.44269504089f;
    return;
  }
  const float* src; unsigned short* dst; int i;
  if (blk < 288)      { src = wq; dst = Wqkv;               i = blk * 256 + threadIdx.x; }
  else if (blk < 576) { src = wk; dst = Wqkv + Cn * Cn;     i = (blk - 288) * 256 + threadIdx.x; }
  else if (blk < 864) { src = wv; dst = Wqkv + 2 * Cn * Cn; i = (blk - 576) * 256 + threadIdx.x; }
  else if (blk < 1152){ src = wo; dst = Wob;                i = (blk - 864) * 256 + threadIdx.x; }
  else if (blk < 2304){ src = w1; dst = W1b;                i = (blk - 1152) * 256 + threadIdx.x; }
  else                { src = w2; dst = W2b;                i = (blk - 2304) * 256 + threadIdx.x; }
  const float4 a = ((const float4*)src)[i * 2];
  const float4 b = ((const float4*)src)[i * 2 + 1];
  *(us8*)&dst[i * 8] = pack8(a, b);
}

// ---- LayerNorm standalone (LN2) ----
__global__ __launch_bounds__(256) void ln_kernel(const float* __restrict__ xin,
    const float* __restrict__ w, const float* __restrict__ bsh,
    unsigned short* __restrict__ out)
{
  __shared__ float sred[8];
  ln_row_body(xin, w, bsh, out, blockIdx.x, sred);
}

// ---- MFMA GEMM 128x128, BK=32 dbuf, counted-vmcnt pipeline (r17 form) ----
// LDS chunk-swizzled: src chunk = (l&3)^((l>>3)&3), read chunk = quad^((nl>>1)&3).
// EPI 0: bf16 out; EPI 1: bf16 out, cols<Cn scaled by QSCALE (Q pre-scale);
// EPI 2: bf16 out = gelu_exact.
template<int EPI, bool TRANSV>
__global__ __launch_bounds__(256) void gemm_mfma_kernel(
    const unsigned short* __restrict__ A, const unsigned short* __restrict__ Bw,
    const float* __restrict__ bias, unsigned short* __restrict__ vt,
    void* __restrict__ Cout, int M, int N, int K, int ldo)
{
  __shared__ __align__(16) unsigned short As[2][128 * 32];  // 2 bufs x 8 KB
  __shared__ __align__(16) unsigned short Bs[2][128 * 32];
  const int tid = threadIdx.x;
  const int lane = tid & 63, w = tid >> 6;
  const int nl = lane & 15, quad = lane >> 4;
  const int wm = w >> 1, wn = w & 1;
  const int id = blockIdx.x;
  const int bm = ((id & 7) * 4 + ((id >> 3) & 3)) * 128;   // XCD-local bm slice
  const int bn = (id >> 5) * 128;
  const int l4 = lane >> 2;
  const int lk = (((lane & 3) ^ ((lane >> 3) & 3)) * 8);   // swizzled src chunk
  const int qsw = (quad ^ ((nl >> 1) & 3)) * 8;            // swizzled read chunk

  f32x4 acc[4][4];
  #pragma unroll
  for (int i = 0; i < 4; i++)
    #pragma unroll
    for (int j = 0; j < 4; j++) acc[i][j] = (f32x4){0.f, 0.f, 0.f, 0.f};

  const int c0 = w, c1 = w + 4;
  const unsigned short* A0 = A + (size_t)(bm + c0 * 16 + l4) * K + lk;
  const unsigned short* A1 = A + (size_t)(bm + c1 * 16 + l4) * K + lk;
  const unsigned short* B0 = Bw + (size_t)(bn + c0 * 16 + l4) * K + lk;
  const unsigned short* B1 = Bw + (size_t)(bn + c1 * 16 + l4) * K + lk;

  // preload tile 0 into buffer 0
  GLDS(A0, &As[0][c0 * 512]); GLDS(A1, &As[0][c1 * 512]);
  GLDS(B0, &Bs[0][c0 * 512]); GLDS(B1, &Bs[0][c1 * 512]);

  const int NIT = K >> 5;
  for (int t = 0; t < NIT; t++){
    const int cur = t & 1;
    SBAR();                          // (A) all waves done reading buf[cur^1]
    if (t + 1 < NIT){                // issue t+1, then wait only the oldest 4
      const int k0 = (t + 1) << 5;
      GLDS(A0 + k0, &As[cur ^ 1][c0 * 512]);
      GLDS(A1 + k0, &As[cur ^ 1][c1 * 512]);
      GLDS(B0 + k0, &Bs[cur ^ 1][c0 * 512]);
      GLDS(B1 + k0, &Bs[cur ^ 1][c1 * 512]);
      WAITVM(4);
    } else {
      WAITVM(0);
    }
    SBAR();                          // (B) every wave's tile-t staging landed
    bfrag Af[4], Bf[4];
    #pragma unroll
    for (int mt = 0; mt < 4; mt++)
      Af[mt] = *(const bfrag*)&As[cur][(wm * 64 + mt * 16 + nl) * 32 + qsw];
    #pragma unroll
    for (int nt = 0; nt < 4; nt++)
      Bf[nt] = *(const bfrag*)&Bs[cur][(wn * 64 + nt * 16 + nl) * 32 + qsw];
    #pragma unroll
    for (int mt = 0; mt < 4; mt++)
      #pragma unroll
      for (int nt = 0; nt < 4; nt++)
        acc[mt][nt] = __builtin_amdgcn_mfma_f32_16x16x32_bf16(Af[mt], Bf[nt], acc[mt][nt], 0, 0, 0);
  }

  if (TRANSV && bn >= 1536){
    #pragma unroll
    for (int nt = 0; nt < 4; nt++){
      const int col = bn + wn * 64 + nt * 16 + nl;
      const float bv_ = bias[col];
      const int vcol = col - 1536;
      #pragma unroll
      for (int mt = 0; mt < 4; mt++){
        const int row0 = bm + wm * 64 + mt * 16 + quad * 4;
        unsigned short pk[4];
        #pragma unroll
        for (int r = 0; r < 4; r++) pk[r] = f2bu(acc[mt][nt][r] + bv_);
        *(uint2*)&vt[(size_t)vcol * Mn + row0] = *(uint2*)pk;
      }
    }
    return;
  }
  #pragma unroll
  for (int nt = 0; nt < 4; nt++){
    const int col = bn + wn * 64 + nt * 16 + nl;
    const float bv_ = bias[col];
    const float sc = (EPI == 1 && col < Cn) ? QSCALE : 1.0f;
    #pragma unroll
    for (int mt = 0; mt < 4; mt++){
      const int row0 = bm + wm * 64 + mt * 16 + quad * 4;
      #pragma unroll
      for (int r = 0; r < 4; r++){
        const size_t idx = (size_t)(row0 + r) * ldo + col;
        const float v = acc[mt][nt][r] + bv_;
        if (EPI == 2){
          ((unsigned short*)Cout)[idx] = f2bu(0.5f * v * (1.f + erff(v * 0.70710678118f)));
        } else {
          ((unsigned short*)Cout)[idx] = f2bu(v * sc);
        }
      }
    }
  }
}

// ---- MFMA GEMM 64x64 tiles, BK=64 split-plane, dbuf counted-vmcnt (r21) ----
// fp32 out = acc+bias+res. id%8 = XCD; XCD owns 8 consecutive bm-blocks.
__global__ __launch_bounds__(256) void gemm_t64_kernel(
    const unsigned short* __restrict__ A, const unsigned short* __restrict__ Bw,
    const float* __restrict__ bias, const float* __restrict__ res,
    float* __restrict__ Cout, int M, int N, int K)
{
  __shared__ __align__(16) unsigned short As[2][2 * 64 * 32];  // [buf][plane][row][32]
  __shared__ __align__(16) unsigned short Bs[2][2 * 64 * 32];
  const int tid = threadIdx.x;
  const int lane = tid & 63, w = tid >> 6;
  const int nl = lane & 15, quad = lane >> 4;
  const int id = blockIdx.x;
  const int bm = ((id & 7) * 8 + ((id >> 3) & 7)) * 64;    // XCD-local bm slice
  const int bn = (id >> 6) * 64;
  const int l2 = lane >> 2;
  const int l3 = (((lane & 3) ^ ((lane >> 3) & 3)) * 8);   // swizzled src chunk
  const int qsw = (quad ^ ((nl >> 1) & 3)) * 8;            // swizzled read chunk

  f32x4 acc[4];
  #pragma unroll
  for (int j = 0; j < 4; j++) acc[j] = (f32x4){0.f, 0.f, 0.f, 0.f};

  const unsigned short* A0 = A + (size_t)(bm + w * 16 + l2) * K + l3;
  const unsigned short* B0 = Bw + (size_t)(bn + w * 16 + l2) * K + l3;

  // preload tile 0 into buffer 0
  GLDS(A0,      &As[0][w * 512]);
  GLDS(A0 + 32, &As[0][2048 + w * 512]);
  GLDS(B0,      &Bs[0][w * 512]);
  GLDS(B0 + 32, &Bs[0][2048 + w * 512]);

  const int NIT = K >> 6;
  for (int t = 0; t < NIT; t++){
    const int cur = t & 1;
    SBAR();                          // (A) all waves done reading buf[cur^1]
    if (t + 1 < NIT){
      const int k0 = (t + 1) << 6;
      GLDS(A0 + k0,      &As[cur ^ 1][w * 512]);
      GLDS(A0 + k0 + 32, &As[cur ^ 1][2048 + w * 512]);
      GLDS(B0 + k0,      &Bs[cur ^ 1][w * 512]);
      GLDS(B0 + k0 + 32, &Bs[cur ^ 1][2048 + w * 512]);
      WAITVM(4);
    } else {
      WAITVM(0);
    }
    SBAR();                          // (B) every wave's tile-t staging landed
    const bfrag Af0 = *(const bfrag*)&As[cur][(w * 16 + nl) * 32 + qsw];
    const bfrag Af1 = *(const bfrag*)&As[cur][2048 + (w * 16 + nl) * 32 + qsw];
    bfrag Bf0[4], Bf1[4];
    #pragma unroll
    for (int nt = 0; nt < 4; nt++){
      Bf0[nt] = *(const bfrag*)&Bs[cur][(nt * 16 + nl) * 32 + qsw];
      Bf1[nt] = *(const bfrag*)&Bs[cur][2048 + (nt * 16 + nl) * 32 + qsw];
    }
    #pragma unroll
    for (int nt = 0; nt < 4; nt++){
      acc[nt] = __builtin_amdgcn_mfma_f32_16x16x32_bf16(Af0, Bf0[nt], acc[nt], 0, 0, 0);
      acc[nt] = __builtin_amdgcn_mfma_f32_16x16x32_bf16(Af1, Bf1[nt], acc[nt], 0, 0, 0);
    }
  }

  const int row0 = bm + w * 16 + quad * 4;
  #pragma unroll
  for (int nt = 0; nt < 4; nt++){
    const int col = bn + nt * 16 + nl;
    const float bv_ = bias[col];
    #pragma unroll
    for (int r = 0; r < 4; r++){
      const size_t idx = (size_t)(row0 + r) * N + col;
      Cout[idx] = acc[nt][r] + bv_ + res[idx];
    }
  }
}

// ---- qmean stage 1: vectorized us8 loads, 64 blocks/batch x 32 rows ----
__global__ __launch_bounds__(256) void qmean_part_kernel(
    const unsigned short* __restrict__ QKVqk, float* __restrict__ qpart)
{
  __shared__ float ps[2][Cn];
  const int b = blockIdx.y, t0 = blockIdx.x * 32;
  const int tid = threadIdx.x;
  if (tid < 192){
    const int cg = (tid % 96) * 8, rh = tid / 96;   // rh in {0,1}
    float acc[8] = {0.f,0.f,0.f,0.f,0.f,0.f,0.f,0.f};
    for (int i = 0; i < 16; i++){
      const int r = t0 + 2 * i + rh;
      const us8 v = *(const us8*)&QKVqk[(size_t)(b * Tn + r) * LQK + cg];
      #pragma unroll
      for (int j = 0; j < 8; j++) acc[j] += bu2f(v[j]);
    }
    #pragma unroll
    for (int j = 0; j < 8; j++) ps[rh][cg + j] = acc[j];
  }
  __syncthreads();
  if (tid < Dn){
    float s = 0.f;
    #pragma unroll
    for (int hh = 0; hh < Hn; hh++)
      s += ps[0][hh * Dn + tid] + ps[1][hh * Dn + tid];
    qpart[(b * 64 + blockIdx.x) * Dn + tid] = s;
  }
}

// ---- gate[b,h] ----  (compensates Q pre-scale by INVQS; 64 partials)
__global__ __launch_bounds__(64) void gate_kernel(const float* __restrict__ qpart,
    const float* __restrict__ gur, const float* __restrict__ gi,
    const float* __restrict__ rsc, float* __restrict__ gate)
{
  const int b = blockIdx.x / Hn, h = blockIdx.x % Hn;
  const int d = threadIdx.x;
  float s = 0.f;
  #pragma unroll
  for (int blk = 0; blk < 64; blk++) s += qpart[(b * 64 + blk) * Dn + d];
  const float g = s * (1.f / (Hn * Tn)) * INVQS;
  float vr = g * gur[h * Dn + d];
  float vu = g * gi[h * Dn + d];
  #pragma unroll
  for (int off = 32; off > 0; off >>= 1){
    vr += __shfl_down(vr, off, 64);
    vu += __shfl_down(vu, off, 64);
  }
  if (d == 0){
    const float gr = 1.f / (1.f + __expf(-vr));
    const float gu = 1.f / (1.f + __expf(-vu));
    gate[blockIdx.x] = 1.f + gu * rsc[h] * gr;
  }
}

// ---- MFMA flash attention; split-vmcnt K/V double-buffer ----
// LDS: Qs 64x72 (dies -> bias_blk) | KsP [2bufs][2planes][64][32] |
//      VtP [2][2][64][32] | Ptq 64x72 | lsh 4x64.  Total 52224 B.
// Loop: sbar(A) -> issue GLDS(t+1) -> preload bias (LDS, drains under wait)
//       -> vmcnt(6) [K(t)] -> QK+softmax -> vmcnt(4) [V(t) under QK] ->
//       lgkm0 -> sbar(B) -> PV.
__global__ __launch_bounds__(256) void attn_mfma_kernel(
    const unsigned short* __restrict__ QKVqk, const unsigned short* __restrict__ VT,
    const float* __restrict__ bias_rel, const float* __restrict__ gate,
    unsigned short* __restrict__ O)
{
  __shared__ __align__(16) char smem[52224];
  unsigned short* Qs = (unsigned short*)smem;            // 64x72, dies -> bias
  float* bias_blk    = (float*)smem;                     // 2111 floats
  unsigned short* KsP = (unsigned short*)(smem + 9216);  // [2][2][64][32]
  unsigned short* VtP = (unsigned short*)(smem + 25600); // [2][2][64][32]
  unsigned short* Ptq = (unsigned short*)(smem + 41984); // [query][key] 64x72
  float* lsh         = (float*)(smem + 51200);           // [wave][query] 4x64

  const int qbase = blockIdx.x * 64;
  const int h = blockIdx.y, b = blockIdx.z;
  const int tid = threadIdx.x;
  const float g = gate[b * Hn + h];
  const float* brow = bias_rel + h * 4095 + 1984 - qbase;
  const unsigned short* Q = QKVqk;
  const unsigned short* K = QKVqk + Cn;

  const int lane = tid & 63, w = tid >> 6;
  const int nl = lane & 15, quad = lane >> 4;
  const int l2 = lane >> 2;
  const int l3 = (((lane & 3) ^ ((lane >> 3) & 3)) * 8);   // swizzled src chunk
  const int qsw = (quad ^ ((nl >> 1) & 3)) * 8;            // swizzled read chunk

  // GLDS staging pointers: wave w stages K-keys/V-dims [w*16, w*16+16)
  const unsigned short* kg0 = K + (size_t)(b * Tn + w * 16 + l2) * LQK + h * Dn + l3;
  const unsigned short* vg0 = VT + (size_t)(h * Dn + w * 16 + l2) * Mn + (size_t)b * Tn + l3;

  // preload tile 0 into buffer 0 (drained by the prologue __syncthreads)
  GLDS(kg0,      KsP + w * 512);
  GLDS(kg0 + 32, KsP + 2048 + w * 512);
  GLDS(vg0,      VtP + w * 512);
  GLDS(vg0 + 32, VtP + 2048 + w * 512);

  // stage Q [query][dim]
  {
    const int row = tid >> 2, cg = (tid & 3) * 16;
    const us8* qp = (const us8*)(Q + (size_t)(b * Tn + qbase + row) * LQK + h * Dn + cg);
    *(us8*)&Qs[row * 72 + cg]     = qp[0];
    *(us8*)&Qs[row * 72 + cg + 8] = qp[1];
  }
  __syncthreads();

  bfrag Qb[4][2];
  #pragma unroll
  for (int mt = 0; mt < 4; mt++){
    Qb[mt][0] = *(const bfrag*)&Qs[(mt * 16 + nl) * 72 + quad * 8];
    Qb[mt][1] = *(const bfrag*)&Qs[(mt * 16 + nl) * 72 + 32 + quad * 8];
  }
  __syncthreads();           // everyone done reading Qs
  for (int j = tid; j < 2111; j += 256) bias_blk[j] = brow[j] * g;
  WAITLG0();                 // own bias writes drained; visible after sbar(A)@t=0

  const int wq = w & 1, wd = w >> 1;
  f32x4 Oa[2][2];            // [query-half a][dim-half d0]
  #pragma unroll
  for (int a = 0; a < 2; a++)
    #pragma unroll
    for (int d0 = 0; d0 < 2; d0++) Oa[a][d0] = (f32x4){0.f, 0.f, 0.f, 0.f};
  float l_part[4] = {0.f, 0.f, 0.f, 0.f};

  for (int kt = 0; kt < 32; kt++){
    const int kbase = kt * 64;
    const int cur = (kt & 1) * 4096;      // element offset of current buffer
    const int nxt = 4096 - cur;
    SBAR();                               // (A) all waves done PV(t-1)
    if (kt < 31){                         // prefetch t+1; keep it flying
      const unsigned short* kg = kg0 + (size_t)(kbase + 64) * LQK;
      const unsigned short* vg = vg0 + kbase + 64;
      GLDS(kg,      KsP + nxt + w * 512);
      GLDS(kg + 32, KsP + nxt + 2048 + w * 512);
      GLDS(vg,      VtP + nxt + w * 512);
      GLDS(vg + 32, VtP + nxt + 2048 + w * 512);
    }

    // preload this tile's bias into registers BEFORE the vmcnt wait:
    // LDS reads independent of VMEM; they drain under the K-load wait.
    const int bofs = kbase + w * 16 + quad * 4 + 63 - nl;
    float bvp[4][4];
    #pragma unroll
    for (int mt = 0; mt < 4; mt++){
      const float* bp = &bias_blk[bofs - mt * 16];
      bvp[mt][0] = bp[0]; bvp[mt][1] = bp[1];
      bvp[mt][2] = bp[2]; bvp[mt][3] = bp[3];
    }

    if (kt < 31){ WAITVM(6); }            // own K(t) landed; V(t) still flying
    else        { WAITVM(2); }            // drain K(31); V(31) still flying

    // S^T: wave w owns key-subtile w (reads ONLY its own staged K rows).
    const bfrag Ka0 = *(const bfrag*)&KsP[cur + (w * 16 + nl) * 32 + qsw];
    const bfrag Ka1 = *(const bfrag*)&KsP[cur + 2048 + (w * 16 + nl) * 32 + qsw];
    #pragma unroll
    for (int mt = 0; mt < 4; mt++){
      f32x4 z = (f32x4){bvp[mt][0], bvp[mt][1], bvp[mt][2], bvp[mt][3]};
      z = __builtin_amdgcn_mfma_f32_16x16x32_bf16(Ka0, Qb[mt][0], z, 0, 0, 0);
      z = __builtin_amdgcn_mfma_f32_16x16x32_bf16(Ka1, Qb[mt][1], z, 0, 0, 0);
      const float p0 = fexp2(z[0]), p1 = fexp2(z[1]);
      const float p2 = fexp2(z[2]), p3 = fexp2(z[3]);
      l_part[mt] += (p0 + p1) + (p2 + p3);
      uint2 pk2;
      asm("v_cvt_pk_bf16_f32 %0, %1, %2" : "=v"(pk2.x) : "v"(p0), "v"(p1));
      asm("v_cvt_pk_bf16_f32 %0, %1, %2" : "=v"(pk2.y) : "v"(p2), "v"(p3));
      *(uint2*)&Ptq[(mt * 16 + nl) * 72 + w * 16 + quad * 4] = pk2;
    }
    if (kt < 31){ WAITVM(4); } else { WAITVM(0); }  // own V(t) landed (under QK)
    WAITLG0();                          // Ptq writes drained (NOT vmcnt)
    SBAR();                             // (B) Ptq + all waves' staging visible

    // O^T += V^T.P : wave (wq, wd): queries wq*32..+31, dims wd*32..+31
    bfrag Vf[2][2], Pf[2][2];
    #pragma unroll
    for (int d0 = 0; d0 < 2; d0++){
      const int dt = wd * 2 + d0;
      Vf[d0][0] = *(const bfrag*)&VtP[cur + (dt * 16 + nl) * 32 + qsw];
      Vf[d0][1] = *(const bfrag*)&VtP[cur + 2048 + (dt * 16 + nl) * 32 + qsw];
    }
    #pragma unroll
    for (int a = 0; a < 2; a++){
      const int qt = wq * 2 + a;
      Pf[a][0] = *(const bfrag*)&Ptq[(qt * 16 + nl) * 72 + quad * 8];
      Pf[a][1] = *(const bfrag*)&Ptq[(qt * 16 + nl) * 72 + 32 + quad * 8];
    }
    #pragma unroll
    for (int a = 0; a < 2; a++)
      #pragma unroll
      for (int d0 = 0; d0 < 2; d0++){
        Oa[a][d0] = __builtin_amdgcn_mfma_f32_16x16x32_bf16(Vf[d0][0], Pf[a][0], Oa[a][d0], 0, 0, 0);
        Oa[a][d0] = __builtin_amdgcn_mfma_f32_16x16x32_bf16(Vf[d0][1], Pf[a][1], Oa[a][d0], 0, 0, 0);
      }
  }

  // ---- epilogue ----
  #pragma unroll
  for (int mt = 0; mt < 4; mt++){
    float l = l_part[mt];
    l += __shfl_xor(l, 16, 64);
    l += __shfl_xor(l, 32, 64);
    if (quad == 0) lsh[w * 64 + mt * 16 + nl] = l;
  }
  __syncthreads();
  #pragma unroll
  for (int a = 0; a < 2; a++){
    const int q = (wq * 2 + a) * 16 + nl;
    const float linv = 1.f / (lsh[q] + lsh[64 + q] + lsh[128 + q] + lsh[192 + q]);
    unsigned short* orow = O + (size_t)(b * Tn + qbase + q) * Cn + h * Dn;
    #pragma unroll
    for (int d0 = 0; d0 < 2; d0++){
      unsigned short pk[4];
      #pragma unroll
      for (int r = 0; r < 4; r++) pk[r] = f2bu(Oa[a][d0][r] * linv);
      *(uint2*)&orow[(wd * 2 + d0) * 16 + quad * 4] = *(uint2*)pk;
    }
  }
}

extern "C" void kernel_launch(void* const* d_in, const int* in_sizes, int n_in,
                              void* d_out, int out_size, void* d_ws, size_t ws_size,
                              hipStream_t stream)
{
  const float* x     = (const float*)d_in[0];
  const float* ln1_w = (const float*)d_in[1];
  const float* ln1_b = (const float*)d_in[2];
  const float* wq    = (const float*)d_in[3];
  const float* bq    = (const float*)d_in[4];
  const float* wk    = (const float*)d_in[5];
  const float* bk    = (const float*)d_in[6];
  const float* wv    = (const float*)d_in[7];
  const float* bv    = (const float*)d_in[8];
  const float* wo    = (const float*)d_in[9];
  const float* bo    = (const float*)d_in[10];
  const float* ln2_w = (const float*)d_in[11];
  const float* ln2_b = (const float*)d_in[12];
  const float* w1    = (const float*)d_in[13];
  const float* b1    = (const float*)d_in[14];
  const float* w2    = (const float*)d_in[15];
  const float* b2    = (const float*)d_in[16];
  const float* rel_embed = (const float*)d_in[17];
  const float* gur   = (const float*)d_in[18];
  const float* gi    = (const float*)d_in[19];
  const float* rsc   = (const float*)d_in[20];

  char* ws = (char*)d_ws;
  unsigned short* QKVqk = (unsigned short*)(ws);
  unsigned short* VT    = (unsigned short*)(ws + 12582912);
  unsigned short* Ob    = (unsigned short*)(ws + 18874368);
  float*          X2    = (float*)(ws + 25165824);
  unsigned short* Hb    = (unsigned short*)(ws + 37748736);
  unsigned short* Wqkv  = (unsigned short*)(ws + 44040192);
  unsigned short* Wob   = (unsigned short*)(ws + 47579136);
  unsigned short* W1b   = (unsigned short*)(ws + 48758784);
  unsigned short* W2b   = (unsigned short*)(ws + 53477376);
  float*          bqkv  = (float*)(ws + 58195968);
  float*          bias_rel = (float*)(ws + 58205184);
  float*          qpart = (float*)(ws + 58401744);   // 2x64x64 fp32 (32 KB)
  float*          gate  = (float*)(ws + 58434560);
  unsigned short* Fb    = (unsigned short*)(ws);   // FFN hidden aliases [0,25165824)

  // 0. fused weight/bias casts + bias_rel table + LN1 (one dispatch)
  cast_ln_kernel<<<3481 + Mn, 256, 0, stream>>>(wq, wk, wv, wo, w1, w2, bq, bk, bv,
                                                rel_embed, Wqkv, Wob, W1b, W2b,
                                                bias_rel, bqkv, x, ln1_w, ln1_b, Hb);
  // 1. fused QKV projection (N=2304): q|k -> QKVqk (Q cols pre-scaled), v -> VT
  gemm_mfma_kernel<1, true><<<(QKVS / 128) * (Mn / 128), 256, 0, stream>>>(
      Hb, Wqkv, bqkv, VT, QKVqk, Mn, QKVS, Cn, LQK);
  // 2. gating scalars (vectorized qmean: 64 blocks/batch x 32 rows)
  qmean_part_kernel<<<dim3(64, 2), 256, 0, stream>>>(QKVqk, qpart);
  gate_kernel<<<2 * Hn, 64, 0, stream>>>(qpart, gur, gi, rsc, gate);
  // 3. MFMA flash attention
  attn_mfma_kernel<<<dim3(Tn / 64, Hn, 2), 256, 0, stream>>>(QKVqk, VT, bias_rel, gate, Ob);
  // 4. output projection + residual -> fp32 X2 (64x64 tiles, XCD-swizzled)
  gemm_t64_kernel<<<(Cn / 64) * (Mn / 64), 256, 0, stream>>>(
      Ob, Wob, bo, x, X2, Mn, Cn, Cn);
  // 5. LN2 -> bf16
  ln_kernel<<<Mn, 256, 0, stream>>>(X2, ln2_w, ln2_b, Hb);
  // 6. FFN
  gemm_mfma_kernel<2, false><<<(FFn / 128) * (Mn / 128), 256, 0, stream>>>(
      Hb, W1b, b1, nullptr, Fb, Mn, FFn, Cn, FFn);
  gemm_t64_kernel<<<(Cn / 64) * (Mn / 64), 256, 0, stream>>>(
      Fb, W2b, b2, X2, (float*)d_out, Mn, Cn, FFn);
}

// Round 16
// 295.592 us; speedup vs baseline: 1.0170x; 1.0170x over previous
//
#include <hip/hip_runtime.h>
#include <hip/hip_bf16.h>

// TransformerLayer: B=2, T=2048, C=768, H=12, D=64, FF=3072. fp32 I/O.
// Round 27: qmean fused into QKV GEMM epilogue. qmean re-read 6.3 MB of Q
// that the EPI=1 epilogue already holds in registers: Q-tiles (bn<768) now
// colsum their scaled output (16 rows/lane -> 2 shuffles across quad ->
// atomicAdd into qsum[2][768]). qsum zeroed by 6 blocks in cast_ln (launch-
// ordered); gate sums 12 head-slots. qmean kernel + launch gap removed.
// attn keeps r26 bias-preload (real per-dispatch win 55.1->54.0).
//
// Workspace layout (bytes):
//   0         QKVqk bf16 4096x1536 (q|k)      }
//   12582912  VT    bf16 768x4096 (V^T)       } Fb (bf16 4096x3072) aliases
//   18874368  Ob    bf16 4096x768             } [0, 25165824)
//   25165824  X2   fp32 4096x768
//   37748736  Hb   bf16 4096x768 (LN1/LN2 out)
//   44040192  Wqkv bf16 2304x768
//   47579136  Wob  bf16 768x768
//   48758784  W1b  bf16 3072x768
//   53477376  W2b  bf16 768x3072
//   58195968  bqkv fp32 2304
//   58205184  bias_rel fp32 12x4095 (pre-scaled by 1/ln2)
//   58401744  qsum fp32 2x768 (atomic colsums of scaled Q)
//   58434560  gate fp32 24

#define Tn 2048
#define Cn 768
#define Hn 12
#define Dn 64
#define FFn 3072
#define Mn 4096
#define QKVS 2304
#define LQK 1536

typedef __attribute__((ext_vector_type(8))) short bfrag;       // 8 bf16 (4 VGPR)
typedef __attribute__((ext_vector_type(8))) unsigned short us8;
typedef __attribute__((ext_vector_type(4))) float f32x4;

#define GLDS(gptr, lptr) __builtin_amdgcn_global_load_lds( \
    (const __attribute__((address_space(1))) void*)(gptr), \
    (__attribute__((address_space(3))) void*)(lptr), 16, 0, 0)

#define SBAR()   __builtin_amdgcn_s_barrier()
#define WAITVM(N) asm volatile("s_waitcnt vmcnt(" #N ")" ::: "memory")
#define WAITLG0() asm volatile("s_waitcnt lgkmcnt(0)" ::: "memory")

#define QSCALE 0.18033688f        // D^-0.5 / ln2, folded into Q at projection
#define INVQS  5.5451774445f      // 8 * ln2, gate compensation

__device__ __forceinline__ unsigned short f2bu(float f){
  __hip_bfloat16 h = __float2bfloat16(f);
  return *(unsigned short*)&h;
}
__device__ __forceinline__ float bu2f(unsigned short u){
  union { unsigned int i; float f; } v; v.i = ((unsigned int)u) << 16; return v.f;
}
__device__ __forceinline__ us8 pack8(float4 a, float4 b){
  us8 c;
  c[0]=f2bu(a.x); c[1]=f2bu(a.y); c[2]=f2bu(a.z); c[3]=f2bu(a.w);
  c[4]=f2bu(b.x); c[5]=f2bu(b.y); c[6]=f2bu(b.z); c[7]=f2bu(b.w);
  return c;
}
__device__ __forceinline__ float fexp2(float x){ return __builtin_amdgcn_exp2f(x); }

// ---- shared LN row body (fp32 in -> bf16 out; float4 loads, 1-pass) ----
__device__ __forceinline__ void ln_row_body(const float* __restrict__ xin,
    const float* __restrict__ w, const float* __restrict__ bsh,
    unsigned short* __restrict__ out, int row, float* sred /*[2][4]*/)
{
  const size_t base = (size_t)row * Cn;
  const int tid = threadIdx.x;
  float4 v = {0.f, 0.f, 0.f, 0.f};
  float s = 0.f, s2 = 0.f;
  if (tid < 192){
    v = *(const float4*)&xin[base + tid * 4];
    s  = (v.x + v.y) + (v.z + v.w);
    s2 = (v.x * v.x + v.y * v.y) + (v.z * v.z + v.w * v.w);
  }
  #pragma unroll
  for (int off = 32; off > 0; off >>= 1){
    s  += __shfl_down(s,  off, 64);
    s2 += __shfl_down(s2, off, 64);
  }
  if ((tid & 63) == 0){ sred[tid >> 6] = s; sred[4 + (tid >> 6)] = s2; }
  __syncthreads();
  const float ts  = (sred[0] + sred[1]) + (sred[2] + sred[3]);
  const float ts2 = (sred[4] + sred[5]) + (sred[6] + sred[7]);
  const float mean = ts * (1.f / Cn);
  const float var  = ts2 * (1.f / Cn) - mean * mean;
  const float rstd = rsqrtf(var + 1e-5f);
  if (tid < 192){
    const float4 wv = *(const float4*)&w[tid * 4];
    const float4 bv = *(const float4*)&bsh[tid * 4];
    const float o0 = (v.x - mean) * rstd * wv.x + bv.x;
    const float o1 = (v.y - mean) * rstd * wv.y + bv.y;
    const float o2 = (v.z - mean) * rstd * wv.z + bv.z;
    const float o3 = (v.w - mean) * rstd * wv.w + bv.w;
    uint2 pk;
    asm("v_cvt_pk_bf16_f32 %0, %1, %2" : "=v"(pk.x) : "v"(o0), "v"(o1));
    asm("v_cvt_pk_bf16_f32 %0, %1, %2" : "=v"(pk.y) : "v"(o2), "v"(o3));
    *(uint2*)&out[base + tid * 4] = pk;
  }
}

// ---- fused weight casts + bias_rel + bqkv + qsum-zero + LN1 ----
// blocks: weights [0,3456); bias_rel [3456,3472); bqkv [3472,3481);
//         qsum zero [3481,3487); LN1 rows [3487, 3487+4096).
__global__ __launch_bounds__(256) void cast_ln_kernel(
    const float* __restrict__ wq, const float* __restrict__ wk,
    const float* __restrict__ wv, const float* __restrict__ wo,
    const float* __restrict__ w1, const float* __restrict__ w2,
    const float* __restrict__ bq, const float* __restrict__ bk,
    const float* __restrict__ bv, const float* __restrict__ rel_embed,
    unsigned short* __restrict__ Wqkv, unsigned short* __restrict__ Wob,
    unsigned short* __restrict__ W1b, unsigned short* __restrict__ W2b,
    float* __restrict__ bias_rel, float* __restrict__ bqkv,
    float* __restrict__ qsum,
    const float* __restrict__ x, const float* __restrict__ ln1_w,
    const float* __restrict__ ln1_b, unsigned short* __restrict__ Hb)
{
  __shared__ float sred[8];
  const int blk = blockIdx.x;
  if (blk >= 3487){
    ln_row_body(x, ln1_w, ln1_b, Hb, blk - 3487, sred);
    return;
  }
  if (blk >= 3481){
    qsum[(blk - 3481) * 256 + threadIdx.x] = 0.f;   // 6*256 = 1536 exactly
    return;
  }
  if (blk >= 3472){
    const int i = (blk - 3472) * 256 + threadIdx.x;   // 0..2303 exactly
    bqkv[i] = (i < Cn) ? bq[i] : (i < 2 * Cn) ? bk[i - Cn] : bv[i - 2 * Cn];
    return;
  }
  if (blk >= 3456){
    const int idx = (blk - 3456) * 256 + threadIdx.x;
    if (idx >= 4095) return;
    const int rel = idx - 2047;
    const int ab = rel < 0 ? -rel : rel;
    int bucket;
    if (ab < 80){
      bucket = ab;
    } else {
      const float lr = logf((float)ab * (1.0f / 80.0f)) * (1.0f / 2.3025851f);
      int lp = 80 + (int)(lr * 80.0f);
      bucket = lp < 159 ? lp : 159;
    }
    if (rel >= 0) bucket += 160;
    #pragma unroll
    for (int h = 0; h < Hn; h++)
      bias_rel[h * 4095 + idx] = rel_embed[bucket * Hn + h] * 1.44269504089f;
    return;
  }
  const float* src; unsigned short* dst; int i;
  if (blk < 288)      { src = wq; dst = Wqkv;               i = blk * 256 + threadIdx.x; }
  else if (blk < 576) { src = wk; dst = Wqkv + Cn * Cn;     i = (blk - 288) * 256 + threadIdx.x; }
  else if (blk < 864) { src = wv; dst = Wqkv + 2 * Cn * Cn; i = (blk - 576) * 256 + threadIdx.x; }
  else if (blk < 1152){ src = wo; dst = Wob;                i = (blk - 864) * 256 + threadIdx.x; }
  else if (blk < 2304){ src = w1; dst = W1b;                i = (blk - 1152) * 256 + threadIdx.x; }
  else                { src = w2; dst = W2b;                i = (blk - 2304) * 256 + threadIdx.x; }
  const float4 a = ((const float4*)src)[i * 2];
  const float4 b = ((const float4*)src)[i * 2 + 1];
  *(us8*)&dst[i * 8] = pack8(a, b);
}

// ---- LayerNorm standalone (LN2) ----
__global__ __launch_bounds__(256) void ln_kernel(const float* __restrict__ xin,
    const float* __restrict__ w, const float* __restrict__ bsh,
    unsigned short* __restrict__ out)
{
  __shared__ float sred[8];
  ln_row_body(xin, w, bsh, out, blockIdx.x, sred);
}

// ---- MFMA GEMM 128x128, BK=32 dbuf, counted-vmcnt pipeline (r17 form) ----
// LDS chunk-swizzled: src chunk = (l&3)^((l>>3)&3), read chunk = quad^((nl>>1)&3).
// EPI 0: bf16 out; EPI 1: bf16 out, cols<Cn scaled by QSCALE + fused qmean
// colsum atomics into qsum[2][768]; EPI 2: bf16 out = gelu_exact.
template<int EPI, bool TRANSV>
__global__ __launch_bounds__(256) void gemm_mfma_kernel(
    const unsigned short* __restrict__ A, const unsigned short* __restrict__ Bw,
    const float* __restrict__ bias, unsigned short* __restrict__ vt,
    void* __restrict__ Cout, float* __restrict__ qsum,
    int M, int N, int K, int ldo)
{
  __shared__ __align__(16) unsigned short As[2][128 * 32];  // 2 bufs x 8 KB
  __shared__ __align__(16) unsigned short Bs[2][128 * 32];
  const int tid = threadIdx.x;
  const int lane = tid & 63, w = tid >> 6;
  const int nl = lane & 15, quad = lane >> 4;
  const int wm = w >> 1, wn = w & 1;
  const int id = blockIdx.x;
  const int bm = ((id & 7) * 4 + ((id >> 3) & 3)) * 128;   // XCD-local bm slice
  const int bn = (id >> 5) * 128;
  const int l4 = lane >> 2;
  const int lk = (((lane & 3) ^ ((lane >> 3) & 3)) * 8);   // swizzled src chunk
  const int qsw = (quad ^ ((nl >> 1) & 3)) * 8;            // swizzled read chunk

  f32x4 acc[4][4];
  #pragma unroll
  for (int i = 0; i < 4; i++)
    #pragma unroll
    for (int j = 0; j < 4; j++) acc[i][j] = (f32x4){0.f, 0.f, 0.f, 0.f};

  const int c0 = w, c1 = w + 4;
  const unsigned short* A0 = A + (size_t)(bm + c0 * 16 + l4) * K + lk;
  const unsigned short* A1 = A + (size_t)(bm + c1 * 16 + l4) * K + lk;
  const unsigned short* B0 = Bw + (size_t)(bn + c0 * 16 + l4) * K + lk;
  const unsigned short* B1 = Bw + (size_t)(bn + c1 * 16 + l4) * K + lk;

  // preload tile 0 into buffer 0
  GLDS(A0, &As[0][c0 * 512]); GLDS(A1, &As[0][c1 * 512]);
  GLDS(B0, &Bs[0][c0 * 512]); GLDS(B1, &Bs[0][c1 * 512]);

  const int NIT = K >> 5;
  for (int t = 0; t < NIT; t++){
    const int cur = t & 1;
    SBAR();                          // (A) all waves done reading buf[cur^1]
    if (t + 1 < NIT){                // issue t+1, then wait only the oldest 4
      const int k0 = (t + 1) << 5;
      GLDS(A0 + k0, &As[cur ^ 1][c0 * 512]);
      GLDS(A1 + k0, &As[cur ^ 1][c1 * 512]);
      GLDS(B0 + k0, &Bs[cur ^ 1][c0 * 512]);
      GLDS(B1 + k0, &Bs[cur ^ 1][c1 * 512]);
      WAITVM(4);
    } else {
      WAITVM(0);
    }
    SBAR();                          // (B) every wave's tile-t staging landed
    bfrag Af[4], Bf[4];
    #pragma unroll
    for (int mt = 0; mt < 4; mt++)
      Af[mt] = *(const bfrag*)&As[cur][(wm * 64 + mt * 16 + nl) * 32 + qsw];
    #pragma unroll
    for (int nt = 0; nt < 4; nt++)
      Bf[nt] = *(const bfrag*)&Bs[cur][(wn * 64 + nt * 16 + nl) * 32 + qsw];
    #pragma unroll
    for (int mt = 0; mt < 4; mt++)
      #pragma unroll
      for (int nt = 0; nt < 4; nt++)
        acc[mt][nt] = __builtin_amdgcn_mfma_f32_16x16x32_bf16(Af[mt], Bf[nt], acc[mt][nt], 0, 0, 0);
  }

  if (TRANSV && bn >= 1536){
    #pragma unroll
    for (int nt = 0; nt < 4; nt++){
      const int col = bn + wn * 64 + nt * 16 + nl;
      const float bv_ = bias[col];
      const int vcol = col - 1536;
      #pragma unroll
      for (int mt = 0; mt < 4; mt++){
        const int row0 = bm + wm * 64 + mt * 16 + quad * 4;
        unsigned short pk[4];
        #pragma unroll
        for (int r = 0; r < 4; r++) pk[r] = f2bu(acc[mt][nt][r] + bv_);
        *(uint2*)&vt[(size_t)vcol * Mn + row0] = *(uint2*)pk;
      }
    }
    return;
  }
  float cs[4] = {0.f, 0.f, 0.f, 0.f};     // fused qmean partial colsums
  #pragma unroll
  for (int nt = 0; nt < 4; nt++){
    const int col = bn + wn * 64 + nt * 16 + nl;
    const float bv_ = bias[col];
    const float sc = (EPI == 1 && col < Cn) ? QSCALE : 1.0f;
    #pragma unroll
    for (int mt = 0; mt < 4; mt++){
      const int row0 = bm + wm * 64 + mt * 16 + quad * 4;
      #pragma unroll
      for (int r = 0; r < 4; r++){
        const size_t idx = (size_t)(row0 + r) * ldo + col;
        const float v = acc[mt][nt][r] + bv_;
        if (EPI == 2){
          ((unsigned short*)Cout)[idx] = f2bu(0.5f * v * (1.f + erff(v * 0.70710678118f)));
        } else {
          const float vs = v * sc;
          ((unsigned short*)Cout)[idx] = f2bu(vs);
          if (EPI == 1) cs[nt] += vs;
        }
      }
    }
  }
  if (EPI == 1 && bn < Cn){
    // reduce colsums across the quad (4 lanes share a col) and atomicAdd
    const int bq_ = bm >> 11;              // batch = bm / 2048
    #pragma unroll
    for (int nt = 0; nt < 4; nt++){
      float s = cs[nt];
      s += __shfl_xor(s, 16, 64);
      s += __shfl_xor(s, 32, 64);
      if (quad == 0){
        const int col = bn + wn * 64 + nt * 16 + nl;
        atomicAdd(&qsum[bq_ * Cn + col], s);
      }
    }
  }
}

// ---- MFMA GEMM 64x64 tiles, BK=64 split-plane, dbuf counted-vmcnt (r21) ----
// fp32 out = acc+bias+res. id%8 = XCD; XCD owns 8 consecutive bm-blocks.
__global__ __launch_bounds__(256) void gemm_t64_kernel(
    const unsigned short* __restrict__ A, const unsigned short* __restrict__ Bw,
    const float* __restrict__ bias, const float* __restrict__ res,
    float* __restrict__ Cout, int M, int N, int K)
{
  __shared__ __align__(16) unsigned short As[2][2 * 64 * 32];  // [buf][plane][row][32]
  __shared__ __align__(16) unsigned short Bs[2][2 * 64 * 32];
  const int tid = threadIdx.x;
  const int lane = tid & 63, w = tid >> 6;
  const int nl = lane & 15, quad = lane >> 4;
  const int id = blockIdx.x;
  const int bm = ((id & 7) * 8 + ((id >> 3) & 7)) * 64;    // XCD-local bm slice
  const int bn = (id >> 6) * 64;
  const int l2 = lane >> 2;
  const int l3 = (((lane & 3) ^ ((lane >> 3) & 3)) * 8);   // swizzled src chunk
  const int qsw = (quad ^ ((nl >> 1) & 3)) * 8;            // swizzled read chunk

  f32x4 acc[4];
  #pragma unroll
  for (int j = 0; j < 4; j++) acc[j] = (f32x4){0.f, 0.f, 0.f, 0.f};

  const unsigned short* A0 = A + (size_t)(bm + w * 16 + l2) * K + l3;
  const unsigned short* B0 = Bw + (size_t)(bn + w * 16 + l2) * K + l3;

  // preload tile 0 into buffer 0
  GLDS(A0,      &As[0][w * 512]);
  GLDS(A0 + 32, &As[0][2048 + w * 512]);
  GLDS(B0,      &Bs[0][w * 512]);
  GLDS(B0 + 32, &Bs[0][2048 + w * 512]);

  const int NIT = K >> 6;
  for (int t = 0; t < NIT; t++){
    const int cur = t & 1;
    SBAR();                          // (A) all waves done reading buf[cur^1]
    if (t + 1 < NIT){
      const int k0 = (t + 1) << 6;
      GLDS(A0 + k0,      &As[cur ^ 1][w * 512]);
      GLDS(A0 + k0 + 32, &As[cur ^ 1][2048 + w * 512]);
      GLDS(B0 + k0,      &Bs[cur ^ 1][w * 512]);
      GLDS(B0 + k0 + 32, &Bs[cur ^ 1][2048 + w * 512]);
      WAITVM(4);
    } else {
      WAITVM(0);
    }
    SBAR();                          // (B) every wave's tile-t staging landed
    const bfrag Af0 = *(const bfrag*)&As[cur][(w * 16 + nl) * 32 + qsw];
    const bfrag Af1 = *(const bfrag*)&As[cur][2048 + (w * 16 + nl) * 32 + qsw];
    bfrag Bf0[4], Bf1[4];
    #pragma unroll
    for (int nt = 0; nt < 4; nt++){
      Bf0[nt] = *(const bfrag*)&Bs[cur][(nt * 16 + nl) * 32 + qsw];
      Bf1[nt] = *(const bfrag*)&Bs[cur][2048 + (nt * 16 + nl) * 32 + qsw];
    }
    #pragma unroll
    for (int nt = 0; nt < 4; nt++){
      acc[nt] = __builtin_amdgcn_mfma_f32_16x16x32_bf16(Af0, Bf0[nt], acc[nt], 0, 0, 0);
      acc[nt] = __builtin_amdgcn_mfma_f32_16x16x32_bf16(Af1, Bf1[nt], acc[nt], 0, 0, 0);
    }
  }

  const int row0 = bm + w * 16 + quad * 4;
  #pragma unroll
  for (int nt = 0; nt < 4; nt++){
    const int col = bn + nt * 16 + nl;
    const float bv_ = bias[col];
    #pragma unroll
    for (int r = 0; r < 4; r++){
      const size_t idx = (size_t)(row0 + r) * N + col;
      Cout[idx] = acc[nt][r] + bv_ + res[idx];
    }
  }
}

// ---- gate[b,h] ----  (reads fused qsum; compensates Q pre-scale by INVQS)
__global__ __launch_bounds__(64) void gate_kernel(const float* __restrict__ qsum,
    const float* __restrict__ gur, const float* __restrict__ gi,
    const float* __restrict__ rsc, float* __restrict__ gate)
{
  const int b = blockIdx.x / Hn, h = blockIdx.x % Hn;
  const int d = threadIdx.x;
  float s = 0.f;
  #pragma unroll
  for (int hh = 0; hh < Hn; hh++) s += qsum[b * Cn + hh * Dn + d];
  const float g = s * (1.f / (Hn * Tn)) * INVQS;
  float vr = g * gur[h * Dn + d];
  float vu = g * gi[h * Dn + d];
  #pragma unroll
  for (int off = 32; off > 0; off >>= 1){
    vr += __shfl_down(vr, off, 64);
    vu += __shfl_down(vu, off, 64);
  }
  if (d == 0){
    const float gr = 1.f / (1.f + __expf(-vr));
    const float gu = 1.f / (1.f + __expf(-vu));
    gate[blockIdx.x] = 1.f + gu * rsc[h] * gr;
  }
}

// ---- MFMA flash attention; split-vmcnt K/V double-buffer + bias preload ----
// LDS: Qs 64x72 (dies -> bias_blk) | KsP [2bufs][2planes][64][32] |
//      VtP [2][2][64][32] | Ptq 64x72 | lsh 4x64.  Total 52224 B.
// Loop: sbar(A) -> issue GLDS(t+1) -> preload bias (LDS, drains under wait)
//       -> vmcnt(6) [K(t)] -> QK+softmax -> vmcnt(4) [V(t) under QK] ->
//       lgkm0 -> sbar(B) -> PV.
__global__ __launch_bounds__(256) void attn_mfma_kernel(
    const unsigned short* __restrict__ QKVqk, const unsigned short* __restrict__ VT,
    const float* __restrict__ bias_rel, const float* __restrict__ gate,
    unsigned short* __restrict__ O)
{
  __shared__ __align__(16) char smem[52224];
  unsigned short* Qs = (unsigned short*)smem;            // 64x72, dies -> bias
  float* bias_blk    = (float*)smem;                     // 2111 floats
  unsigned short* KsP = (unsigned short*)(smem + 9216);  // [2][2][64][32]
  unsigned short* VtP = (unsigned short*)(smem + 25600); // [2][2][64][32]
  unsigned short* Ptq = (unsigned short*)(smem + 41984); // [query][key] 64x72
  float* lsh         = (float*)(smem + 51200);           // [wave][query] 4x64

  const int qbase = blockIdx.x * 64;
  const int h = blockIdx.y, b = blockIdx.z;
  const int tid = threadIdx.x;
  const float g = gate[b * Hn + h];
  const float* brow = bias_rel + h * 4095 + 1984 - qbase;
  const unsigned short* Q = QKVqk;
  const unsigned short* K = QKVqk + Cn;

  const int lane = tid & 63, w = tid >> 6;
  const int nl = lane & 15, quad = lane >> 4;
  const int l2 = lane >> 2;
  const int l3 = (((lane & 3) ^ ((lane >> 3) & 3)) * 8);   // swizzled src chunk
  const int qsw = (quad ^ ((nl >> 1) & 3)) * 8;            // swizzled read chunk

  // GLDS staging pointers: wave w stages K-keys/V-dims [w*16, w*16+16)
  const unsigned short* kg0 = K + (size_t)(b * Tn + w * 16 + l2) * LQK + h * Dn + l3;
  const unsigned short* vg0 = VT + (size_t)(h * Dn + w * 16 + l2) * Mn + (size_t)b * Tn + l3;

  // preload tile 0 into buffer 0 (drained by the prologue __syncthreads)
  GLDS(kg0,      KsP + w * 512);
  GLDS(kg0 + 32, KsP + 2048 + w * 512);
  GLDS(vg0,      VtP + w * 512);
  GLDS(vg0 + 32, VtP + 2048 + w * 512);

  // stage Q [query][dim]
  {
    const int row = tid >> 2, cg = (tid & 3) * 16;
    const us8* qp = (const us8*)(Q + (size_t)(b * Tn + qbase + row) * LQK + h * Dn + cg);
    *(us8*)&Qs[row * 72 + cg]     = qp[0];
    *(us8*)&Qs[row * 72 + cg + 8] = qp[1];
  }
  __syncthreads();

  bfrag Qb[4][2];
  #pragma unroll
  for (int mt = 0; mt < 4; mt++){
    Qb[mt][0] = *(const bfrag*)&Qs[(mt * 16 + nl) * 72 + quad * 8];
    Qb[mt][1] = *(const bfrag*)&Qs[(mt * 16 + nl) * 72 + 32 + quad * 8];
  }
  __syncthreads();           // everyone done reading Qs
  for (int j = tid; j < 2111; j += 256) bias_blk[j] = brow[j] * g;
  WAITLG0();                 // own bias writes drained; visible after sbar(A)@t=0

  const int wq = w & 1, wd = w >> 1;
  f32x4 Oa[2][2];            // [query-half a][dim-half d0]
  #pragma unroll
  for (int a = 0; a < 2; a++)
    #pragma unroll
    for (int d0 = 0; d0 < 2; d0++) Oa[a][d0] = (f32x4){0.f, 0.f, 0.f, 0.f};
  float l_part[4] = {0.f, 0.f, 0.f, 0.f};

  for (int kt = 0; kt < 32; kt++){
    const int kbase = kt * 64;
    const int cur = (kt & 1) * 4096;      // element offset of current buffer
    const int nxt = 4096 - cur;
    SBAR();                               // (A) all waves done PV(t-1)
    if (kt < 31){                         // prefetch t+1; keep it flying
      const unsigned short* kg = kg0 + (size_t)(kbase + 64) * LQK;
      const unsigned short* vg = vg0 + kbase + 64;
      GLDS(kg,      KsP + nxt + w * 512);
      GLDS(kg + 32, KsP + nxt + 2048 + w * 512);
      GLDS(vg,      VtP + nxt + w * 512);
      GLDS(vg + 32, VtP + nxt + 2048 + w * 512);
    }

    // preload this tile's bias into registers BEFORE the vmcnt wait:
    // LDS reads independent of VMEM; they drain under the K-load wait.
    const int bofs = kbase + w * 16 + quad * 4 + 63 - nl;
    float bvp[4][4];
    #pragma unroll
    for (int mt = 0; mt < 4; mt++){
      const float* bp = &bias_blk[bofs - mt * 16];
      bvp[mt][0] = bp[0]; bvp[mt][1] = bp[1];
      bvp[mt][2] = bp[2]; bvp[mt][3] = bp[3];
    }

    if (kt < 31){ WAITVM(6); }            // own K(t) landed; V(t) still flying
    else        { WAITVM(2); }            // drain K(31); V(31) still flying

    // S^T: wave w owns key-subtile w (reads ONLY its own staged K rows).
    const bfrag Ka0 = *(const bfrag*)&KsP[cur + (w * 16 + nl) * 32 + qsw];
    const bfrag Ka1 = *(const bfrag*)&KsP[cur + 2048 + (w * 16 + nl) * 32 + qsw];
    #pragma unroll
    for (int mt = 0; mt < 4; mt++){
      f32x4 z = (f32x4){bvp[mt][0], bvp[mt][1], bvp[mt][2], bvp[mt][3]};
      z = __builtin_amdgcn_mfma_f32_16x16x32_bf16(Ka0, Qb[mt][0], z, 0, 0, 0);
      z = __builtin_amdgcn_mfma_f32_16x16x32_bf16(Ka1, Qb[mt][1], z, 0, 0, 0);
      const float p0 = fexp2(z[0]), p1 = fexp2(z[1]);
      const float p2 = fexp2(z[2]), p3 = fexp2(z[3]);
      l_part[mt] += (p0 + p1) + (p2 + p3);
      uint2 pk2;
      asm("v_cvt_pk_bf16_f32 %0, %1, %2" : "=v"(pk2.x) : "v"(p0), "v"(p1));
      asm("v_cvt_pk_bf16_f32 %0, %1, %2" : "=v"(pk2.y) : "v"(p2), "v"(p3));
      *(uint2*)&Ptq[(mt * 16 + nl) * 72 + w * 16 + quad * 4] = pk2;
    }
    if (kt < 31){ WAITVM(4); } else { WAITVM(0); }  // own V(t) landed (under QK)
    WAITLG0();                          // Ptq writes drained (NOT vmcnt)
    SBAR();                             // (B) Ptq + all waves' staging visible

    // O^T += V^T.P : wave (wq, wd): queries wq*32..+31, dims wd*32..+31
    bfrag Vf[2][2], Pf[2][2];
    #pragma unroll
    for (int d0 = 0; d0 < 2; d0++){
      const int dt = wd * 2 + d0;
      Vf[d0][0] = *(const bfrag*)&VtP[cur + (dt * 16 + nl) * 32 + qsw];
      Vf[d0][1] = *(const bfrag*)&VtP[cur + 2048 + (dt * 16 + nl) * 32 + qsw];
    }
    #pragma unroll
    for (int a = 0; a < 2; a++){
      const int qt = wq * 2 + a;
      Pf[a][0] = *(const bfrag*)&Ptq[(qt * 16 + nl) * 72 + quad * 8];
      Pf[a][1] = *(const bfrag*)&Ptq[(qt * 16 + nl) * 72 + 32 + quad * 8];
    }
    #pragma unroll
    for (int a = 0; a < 2; a++)
      #pragma unroll
      for (int d0 = 0; d0 < 2; d0++){
        Oa[a][d0] = __builtin_amdgcn_mfma_f32_16x16x32_bf16(Vf[d0][0], Pf[a][0], Oa[a][d0], 0, 0, 0);
        Oa[a][d0] = __builtin_amdgcn_mfma_f32_16x16x32_bf16(Vf[d0][1], Pf[a][1], Oa[a][d0], 0, 0, 0);
      }
  }

  // ---- epilogue ----
  #pragma unroll
  for (int mt = 0; mt < 4; mt++){
    float l = l_part[mt];
    l += __shfl_xor(l, 16, 64);
    l += __shfl_xor(l, 32, 64);
    if (quad == 0) lsh[w * 64 + mt * 16 + nl] = l;
  }
  __syncthreads();
  #pragma unroll
  for (int a = 0; a < 2; a++){
    const int q = (wq * 2 + a) * 16 + nl;
    const float linv = 1.f / (lsh[q] + lsh[64 + q] + lsh[128 + q] + lsh[192 + q]);
    unsigned short* orow = O + (size_t)(b * Tn + qbase + q) * Cn + h * Dn;
    #pragma unroll
    for (int d0 = 0; d0 < 2; d0++){
      unsigned short pk[4];
      #pragma unroll
      for (int r = 0; r < 4; r++) pk[r] = f2bu(Oa[a][d0][r] * linv);
      *(uint2*)&orow[(wd * 2 + d0) * 16 + quad * 4] = *(uint2*)pk;
    }
  }
}

extern "C" void kernel_launch(void* const* d_in, const int* in_sizes, int n_in,
                              void* d_out, int out_size, void* d_ws, size_t ws_size,
                              hipStream_t stream)
{
  const float* x     = (const float*)d_in[0];
  const float* ln1_w = (const float*)d_in[1];
  const float* ln1_b = (const float*)d_in[2];
  const float* wq    = (const float*)d_in[3];
  const float* bq    = (const float*)d_in[4];
  const float* wk    = (const float*)d_in[5];
  const float* bk    = (const float*)d_in[6];
  const float* wv    = (const float*)d_in[7];
  const float* bv    = (const float*)d_in[8];
  const float* wo    = (const float*)d_in[9];
  const float* bo    = (const float*)d_in[10];
  const float* ln2_w = (const float*)d_in[11];
  const float* ln2_b = (const float*)d_in[12];
  const float* w1    = (const float*)d_in[13];
  const float* b1    = (const float*)d_in[14];
  const float* w2    = (const float*)d_in[15];
  const float* b2    = (const float*)d_in[16];
  const float* rel_embed = (const float*)d_in[17];
  const float* gur   = (const float*)d_in[18];
  const float* gi    = (const float*)d_in[19];
  const float* rsc   = (const float*)d_in[20];

  char* ws = (char*)d_ws;
  unsigned short* QKVqk = (unsigned short*)(ws);
  unsigned short* VT    = (unsigned short*)(ws + 12582912);
  unsigned short* Ob    = (unsigned short*)(ws + 18874368);
  float*          X2    = (float*)(ws + 25165824);
  unsigned short* Hb    = (unsigned short*)(ws + 37748736);
  unsigned short* Wqkv  = (unsigned short*)(ws + 44040192);
  unsigned short* Wob   = (unsigned short*)(ws + 47579136);
  unsigned short* W1b   = (unsigned short*)(ws + 48758784);
  unsigned short* W2b   = (unsigned short*)(ws + 53477376);
  float*          bqkv  = (float*)(ws + 58195968);
  float*          bias_rel = (float*)(ws + 58205184);
  float*          qsum  = (float*)(ws + 58401744);   // 2x768 fp32 (atomic)
  float*          gate  = (float*)(ws + 58434560);
  unsigned short* Fb    = (unsigned short*)(ws);   // FFN hidden aliases [0,25165824)

  // 0. fused weight/bias casts + bias_rel + qsum-zero + LN1 (one dispatch)
  cast_ln_kernel<<<3487 + Mn, 256, 0, stream>>>(wq, wk, wv, wo, w1, w2, bq, bk, bv,
                                                rel_embed, Wqkv, Wob, W1b, W2b,
                                                bias_rel, bqkv, qsum,
                                                x, ln1_w, ln1_b, Hb);
  // 1. fused QKV projection (N=2304): q|k -> QKVqk (Q pre-scaled + fused
  //    qmean atomics), v -> VT transposed
  gemm_mfma_kernel<1, true><<<(QKVS / 128) * (Mn / 128), 256, 0, stream>>>(
      Hb, Wqkv, bqkv, VT, QKVqk, qsum, Mn, QKVS, Cn, LQK);
  // 2. gating scalars (qsum already accumulated by the GEMM epilogue)
  gate_kernel<<<2 * Hn, 64, 0, stream>>>(qsum, gur, gi, rsc, gate);
  // 3. MFMA flash attention
  attn_mfma_kernel<<<dim3(Tn / 64, Hn, 2), 256, 0, stream>>>(QKVqk, VT, bias_rel, gate, Ob);
  // 4. output projection + residual -> fp32 X2 (64x64 tiles, XCD-swizzled)
  gemm_t64_kernel<<<(Cn / 64) * (Mn / 64), 256, 0, stream>>>(
      Ob, Wob, bo, x, X2, Mn, Cn, Cn);
  // 5. LN2 -> bf16
  ln_kernel<<<Mn, 256, 0, stream>>>(X2, ln2_w, ln2_b, Hb);
  // 6. FFN
  gemm_mfma_kernel<2, false><<<(FFn / 128) * (Mn / 128), 256, 0, stream>>>(
      Hb, W1b, b1, nullptr, Fb, nullptr, Mn, FFn, Cn, FFn);
  gemm_t64_kernel<<<(Cn / 64) * (Mn / 64), 256, 0, stream>>>(
      Fb, W2b, b2, X2, (float*)d_out, Mn, Cn, FFn);
}